// Round 1
// baseline (730.393 us; speedup 1.0000x reference)
//
#include <hip/hip_runtime.h>

#define SQ   2048
#define DIMD 2048
#define NH   16
#define HD   128
#define MR   4096   // B*S

using u16 = unsigned short;
using u32 = unsigned int;
using s16x8 = __attribute__((ext_vector_type(8))) short;
using u16x8 = __attribute__((ext_vector_type(8))) unsigned short;
using f32x4 = __attribute__((ext_vector_type(4))) float;
using as3u  = __attribute__((address_space(3))) u32;
using as1u  = __attribute__((address_space(1))) u32;

__device__ __forceinline__ u16 f2bf(float f) {
  u32 x = __float_as_uint(f);
  return (u16)((x + 0x7fffu + ((x >> 16) & 1u)) >> 16);
}
__device__ __forceinline__ float bf2f(u16 u) {
  return __uint_as_float(((u32)u) << 16);
}
__device__ __forceinline__ void gld16(const void* g, void* l) {
  __builtin_amdgcn_global_load_lds((as1u*)g, (as3u*)l, 16, 0, 0);
}

// ---------------- fp32 -> bf16 convert ----------------
__global__ __launch_bounds__(256) void cvt_bf16(const float* __restrict__ s,
                                                u16* __restrict__ d, int n4) {
  int i = blockIdx.x * 256 + threadIdx.x;
  int st = gridDim.x * 256;
  for (; i < n4; i += st) {
    float4 v = ((const float4*)s)[i];
    u32 lo = (u32)f2bf(v.x) | ((u32)f2bf(v.y) << 16);
    u32 hi = (u32)f2bf(v.z) | ((u32)f2bf(v.w) << 16);
    ((uint2*)d)[i] = make_uint2(lo, hi);
  }
}

// ---------------- RoPE (1 wave = 1 row of 128) ----------------
__global__ __launch_bounds__(256) void rope_kernel(
    const u16* __restrict__ Qin, const u16* __restrict__ Kin,
    u16* __restrict__ Qout, u16* __restrict__ Kout,
    const float* __restrict__ cosT, const float* __restrict__ sinT) {
  int ten = blockIdx.y;
  const u16* in = ten ? Kin : Qin;
  u16* outp     = ten ? Kout : Qout;
  float scl     = ten ? 1.0f : 0.08838834764831845f;  // fold 1/sqrt(DH) into Q
  int row = blockIdx.x * 4 + (threadIdx.x >> 6);
  int j   = threadIdx.x & 63;
  int s   = row & (SQ - 1);
  const u16* r = in + (size_t)row * HD;
  u16* w = outp + (size_t)row * HD;
  float c  = cosT[s * HD + j];
  float si = sinT[s * HD + j];
  float a  = bf2f(r[j]);
  float b  = bf2f(r[j + 64]);
  float ev = bf2f(r[2 * j]);
  float od = bf2f(r[2 * j + 1]);
  w[j]      = f2bf((a * c - od * si) * scl);
  w[j + 64] = f2bf((b * c + ev * si) * scl);
}

// ---------------- V (b,h,s,dh) -> Vt (b,h,dh,s) ----------------
__global__ __launch_bounds__(256) void transpose_v(const u16* __restrict__ V,
                                                   u16* __restrict__ Vt) {
  __shared__ u16 tile[64][72];
  int sb = blockIdx.x, db = blockIdx.y, bh = blockIdx.z;
  int r  = threadIdx.x >> 3;
  int c8 = (threadIdx.x & 7) * 8;
  const u16* src = V + ((size_t)bh * SQ + sb * 64) * HD + db * 64;
#pragma unroll
  for (int p2 = 0; p2 < 2; p2++) {
    int row = p2 * 32 + r;
    u16x8 v = *(const u16x8*)(src + (size_t)row * HD + c8);
#pragma unroll
    for (int k2 = 0; k2 < 8; k2++) tile[row][c8 + k2] = v[k2];
  }
  __syncthreads();
  u16* dst = Vt + ((size_t)bh * HD + db * 64) * SQ + sb * 64;
#pragma unroll
  for (int p2 = 0; p2 < 2; p2++) {
    int dr = p2 * 32 + r;
    u16x8 o;
#pragma unroll
    for (int k2 = 0; k2 < 8; k2++) o[k2] = tile[c8 + k2][dr];
    *(u16x8*)(dst + (size_t)dr * SQ + c8) = o;
  }
}

// ---------------- GEMM C = A(M,K) * W(N,K)^T  (m97 structure) ----------------
// MODE 0: QKV -> bf16, scattered to (b,h,s,dh); select W/out by blockIdx.y
// MODE 1: O-proj -> fp32 row-major
template <int MODE>
__global__ __launch_bounds__(256) void gemm_bt(
    const u16* __restrict__ A,
    const u16* __restrict__ W0, const u16* __restrict__ W1, const u16* __restrict__ W2,
    u16* __restrict__ O0, u16* __restrict__ O1, u16* __restrict__ O2,
    float* __restrict__ Ofp) {
  __shared__ alignas(16) u16 lA[2][128 * 32];
  __shared__ alignas(16) u16 lB[2][128 * 32];
  int t = threadIdx.x;
  int l = t & 63, l15 = l & 15, lg = l >> 4;
  int wid = t >> 6, wr = wid >> 1, wc = wid & 1;
  int mi = blockIdx.x >> 4, ni = blockIdx.x & 15;
  int m0 = mi * 128, n0 = ni * 128;
  const u16* W = W0;
  u16* Ob = O0;
  if (MODE == 0) {
    if (blockIdx.y == 1) { W = W1; Ob = O1; }
    else if (blockIdx.y == 2) { W = W2; Ob = O2; }
  }
  const u16* Ag = A + (size_t)m0 * DIMD;
  const u16* Wg = W + (size_t)n0 * DIMD;
  int r0 = t >> 2, ch = (t & 3) * 8;

  f32x4 acc[4][4];
#pragma unroll
  for (int a1 = 0; a1 < 4; a1++)
#pragma unroll
    for (int b1 = 0; b1 < 4; b1++) acc[a1][b1] = (f32x4){0.f, 0.f, 0.f, 0.f};

  auto stage = [&](int buf, int kb) {
    int k0 = kb * 32;
    gld16(Ag + (size_t)r0 * DIMD + k0 + ch,        &lA[buf][t * 8]);
    gld16(Ag + (size_t)(r0 + 64) * DIMD + k0 + ch, &lA[buf][(t + 256) * 8]);
    gld16(Wg + (size_t)r0 * DIMD + k0 + ch,        &lB[buf][t * 8]);
    gld16(Wg + (size_t)(r0 + 64) * DIMD + k0 + ch, &lB[buf][(t + 256) * 8]);
  };

  stage(0, 0);
  __syncthreads();
#pragma unroll 2
  for (int kb = 0; kb < DIMD / 32; kb++) {
    if (kb + 1 < DIMD / 32) stage((kb + 1) & 1, kb + 1);
    int buf = kb & 1;
    s16x8 af[4], bfr[4];
#pragma unroll
    for (int rb = 0; rb < 4; rb++)
      af[rb] = *(const s16x8*)&lA[buf][(wr * 64 + rb * 16 + l15) * 32 + lg * 8];
#pragma unroll
    for (int cb = 0; cb < 4; cb++)
      bfr[cb] = *(const s16x8*)&lB[buf][(wc * 64 + cb * 16 + l15) * 32 + lg * 8];
#pragma unroll
    for (int rb = 0; rb < 4; rb++)
#pragma unroll
      for (int cb = 0; cb < 4; cb++)
        acc[rb][cb] = __builtin_amdgcn_mfma_f32_16x16x32_bf16(af[rb], bfr[cb], acc[rb][cb], 0, 0, 0);
    __syncthreads();
  }
#pragma unroll
  for (int rb = 0; rb < 4; rb++) {
#pragma unroll
    for (int cb = 0; cb < 4; cb++) {
#pragma unroll
      for (int i = 0; i < 4; i++) {
        float v = acc[rb][cb][i];
        int mm = m0 + wr * 64 + rb * 16 + lg * 4 + i;
        int nn = n0 + wc * 64 + cb * 16 + l15;
        if (MODE == 0) {
          int b = mm >> 11, s2 = mm & (SQ - 1), h = nn >> 7, dh = nn & (HD - 1);
          Ob[((size_t)(b * NH + h) * SQ + s2) * HD + dh] = f2bf(v);
        } else {
          Ofp[(size_t)mm * DIMD + nn] = v;
        }
      }
    }
  }
}

// ---------------- flash attention ----------------
// grid (S/64, B*H); 4 waves/block, each wave: 16 q-rows, KBLK=64.
// K and Vt fragments read directly from global (L2-resident per bh).
__global__ __launch_bounds__(256) void attn_kernel(
    const u16* __restrict__ Q, const u16* __restrict__ K,
    const u16* __restrict__ Vt, u16* __restrict__ Aout) {
  __shared__ alignas(16) u16 Pl[4][16][72];
  int qb = blockIdx.x, bh = blockIdx.y;
  int wid = threadIdx.x >> 6, l = threadIdx.x & 63;
  int l15 = l & 15, lg = l >> 4;
  int q0 = qb * 64 + wid * 16;
  const u16* Qb = Q + ((size_t)bh * SQ + q0) * HD;
  const u16* Kb = K + (size_t)bh * SQ * HD;
  const u16* Vb = Vt + (size_t)bh * HD * SQ;

  s16x8 qf[4];
#pragma unroll
  for (int ks = 0; ks < 4; ks++)
    qf[ks] = *(const s16x8*)(Qb + (size_t)l15 * HD + ks * 32 + lg * 8);

  f32x4 acc[8];
#pragma unroll
  for (int i = 0; i < 8; i++) acc[i] = (f32x4){0.f, 0.f, 0.f, 0.f};
  float m[4], lsum[4];
#pragma unroll
  for (int i = 0; i < 4; i++) { m[i] = -3.0e38f; lsum[i] = 0.f; }

#pragma unroll 1
  for (int kb = 0; kb < SQ / 64; kb++) {
    const u16* Kt = Kb + (size_t)kb * 64 * HD;
    f32x4 sa[4];
#pragma unroll
    for (int cb = 0; cb < 4; cb++) sa[cb] = (f32x4){0.f, 0.f, 0.f, 0.f};
#pragma unroll
    for (int ks = 0; ks < 4; ks++) {
#pragma unroll
      for (int cb = 0; cb < 4; cb++) {
        s16x8 kf = *(const s16x8*)(Kt + (size_t)(cb * 16 + l15) * HD + ks * 32 + lg * 8);
        sa[cb] = __builtin_amdgcn_mfma_f32_16x16x32_bf16(qf[ks], kf, sa[cb], 0, 0, 0);
      }
    }
    // online softmax: row = lg*4+i, 64 scores spread over 16 lanes x 4 col-blocks
    float rm[4];
#pragma unroll
    for (int i = 0; i < 4; i++)
      rm[i] = fmaxf(fmaxf(sa[0][i], sa[1][i]), fmaxf(sa[2][i], sa[3][i]));
#pragma unroll
    for (int d = 1; d < 16; d <<= 1)
#pragma unroll
      for (int i = 0; i < 4; i++) rm[i] = fmaxf(rm[i], __shfl_xor(rm[i], d));
    float al[4];
#pragma unroll
    for (int i = 0; i < 4; i++) {
      float mn = fmaxf(m[i], rm[i]);
      al[i] = __expf(m[i] - mn);
      m[i] = mn;
    }
    float p[4][4];
#pragma unroll
    for (int cb = 0; cb < 4; cb++)
#pragma unroll
      for (int i = 0; i < 4; i++) p[cb][i] = __expf(sa[cb][i] - m[i]);
    float ps[4];
#pragma unroll
    for (int i = 0; i < 4; i++) ps[i] = p[0][i] + p[1][i] + p[2][i] + p[3][i];
#pragma unroll
    for (int d = 1; d < 16; d <<= 1)
#pragma unroll
      for (int i = 0; i < 4; i++) ps[i] += __shfl_xor(ps[i], d);
#pragma unroll
    for (int i = 0; i < 4; i++) lsum[i] = lsum[i] * al[i] + ps[i];
#pragma unroll
    for (int c2 = 0; c2 < 8; c2++)
#pragma unroll
      for (int i = 0; i < 4; i++) acc[c2][i] *= al[i];
    // P -> LDS (transpose to A-fragment layout); per-wave buffer, no barrier needed
#pragma unroll
    for (int cb = 0; cb < 4; cb++)
#pragma unroll
      for (int i = 0; i < 4; i++)
        Pl[wid][lg * 4 + i][cb * 16 + l15] = f2bf(p[cb][i]);
    asm volatile("s_waitcnt lgkmcnt(0)" ::: "memory");
    s16x8 pf[2];
#pragma unroll
    for (int k2 = 0; k2 < 2; k2++)
      pf[k2] = *(const s16x8*)&Pl[wid][l15][k2 * 32 + lg * 8];
    const u16* Vkb = Vb + kb * 64;
#pragma unroll
    for (int c2 = 0; c2 < 8; c2++) {
#pragma unroll
      for (int k2 = 0; k2 < 2; k2++) {
        s16x8 vf = *(const s16x8*)(Vkb + (size_t)(c2 * 16 + l15) * SQ + k2 * 32 + lg * 8);
        acc[c2] = __builtin_amdgcn_mfma_f32_16x16x32_bf16(pf[k2], vf, acc[c2], 0, 0, 0);
      }
    }
  }
  float rin[4];
#pragma unroll
  for (int i = 0; i < 4; i++) rin[i] = 1.0f / lsum[i];
  int b = bh >> 4, h = bh & (NH - 1);
#pragma unroll
  for (int c2 = 0; c2 < 8; c2++) {
#pragma unroll
    for (int i = 0; i < 4; i++) {
      int q = q0 + lg * 4 + i;
      int dh = c2 * 16 + l15;
      Aout[((size_t)b * SQ + q) * DIMD + h * HD + dh] = f2bf(acc[c2][i] * rin[i]);
    }
  }
}

extern "C" void kernel_launch(void* const* d_in, const int* in_sizes, int n_in,
                              void* d_out, int out_size, void* d_ws, size_t ws_size,
                              hipStream_t stream) {
  (void)in_sizes; (void)n_in; (void)out_size; (void)ws_size;
  const float* x    = (const float*)d_in[0];
  const float* wq   = (const float*)d_in[1];
  const float* wk   = (const float*)d_in[2];
  const float* wv   = (const float*)d_in[3];
  const float* wo   = (const float*)d_in[4];
  const float* cosT = (const float*)d_in[5];
  const float* sinT = (const float*)d_in[6];
  float* out = (float*)d_out;

  char* p = (char*)d_ws;
  const size_t SZ_MD = (size_t)MR * DIMD * 2;    // 16.78 MB
  const size_t SZ_W  = (size_t)DIMD * DIMD * 2;  // 8.39 MB
  u16* xb   = (u16*)p; p += SZ_MD;
  u16* wqb  = (u16*)p; p += SZ_W;
  u16* wkb  = (u16*)p; p += SZ_W;
  u16* wvb  = (u16*)p; p += SZ_W;
  u16* wob  = (u16*)p; p += SZ_W;
  u16* Qraw = (u16*)p; p += SZ_MD;
  u16* Kraw = (u16*)p; p += SZ_MD;
  u16* Qr   = (u16*)p; p += SZ_MD;
  u16* Kr   = (u16*)p; p += SZ_MD;
  u16* Vb   = (u16*)p; p += SZ_MD;
  u16* Vt   = (u16*)p; p += SZ_MD;
  u16* attnout = Qraw;  // Qraw dead after rope; reuse

  cvt_bf16<<<1024, 256, 0, stream>>>(x,  xb,  MR * DIMD / 4);
  cvt_bf16<<<512,  256, 0, stream>>>(wq, wqb, DIMD * DIMD / 4);
  cvt_bf16<<<512,  256, 0, stream>>>(wk, wkb, DIMD * DIMD / 4);
  cvt_bf16<<<512,  256, 0, stream>>>(wv, wvb, DIMD * DIMD / 4);
  cvt_bf16<<<512,  256, 0, stream>>>(wo, wob, DIMD * DIMD / 4);

  gemm_bt<0><<<dim3(512, 3), 256, 0, stream>>>(xb, wqb, wkb, wvb, Qraw, Kraw, Vb, nullptr);
  rope_kernel<<<dim3(16384, 2), 256, 0, stream>>>(Qraw, Kraw, Qr, Kr, cosT, sinT);
  transpose_v<<<dim3(32, 2, 32), 256, 0, stream>>>(Vb, Vt);
  attn_kernel<<<dim3(SQ / 64, 32), 256, 0, stream>>>(Qr, Kr, Vt, attnout);
  gemm_bt<1><<<dim3(512, 1), 256, 0, stream>>>(attnout, wob, nullptr, nullptr,
                                               nullptr, nullptr, nullptr, out);
}

// Round 2
// 372.807 us; speedup vs baseline: 1.9592x; 1.9592x over previous
//
#include <hip/hip_runtime.h>

#define SQ   2048
#define DIMD 2048
#define NH   16
#define HD   128
#define MR   4096   // B*S
#define QBLK 128
#define KBLK 64

using u16 = unsigned short;
using u32 = unsigned int;
using s16x8 = __attribute__((ext_vector_type(8))) short;
using u16x8 = __attribute__((ext_vector_type(8))) unsigned short;
using f32x4 = __attribute__((ext_vector_type(4))) float;
using as3u  = __attribute__((address_space(3))) u32;
using as1u  = __attribute__((address_space(1))) u32;

__device__ __forceinline__ u16 f2bf(float f) {
  u32 x = __float_as_uint(f);
  return (u16)((x + 0x7fffu + ((x >> 16) & 1u)) >> 16);
}
__device__ __forceinline__ float bf2f(u16 u) {
  return __uint_as_float(((u32)u) << 16);
}
__device__ __forceinline__ void gld16(const void* g, void* l) {
  __builtin_amdgcn_global_load_lds((as1u*)g, (as3u*)l, 16, 0, 0);
}

// ---------------- fp32 -> bf16 convert ----------------
__global__ __launch_bounds__(256) void cvt_bf16(const float* __restrict__ s,
                                                u16* __restrict__ d, int n4) {
  int i = blockIdx.x * 256 + threadIdx.x;
  int st = gridDim.x * 256;
  for (; i < n4; i += st) {
    float4 v = ((const float4*)s)[i];
    u32 lo = (u32)f2bf(v.x) | ((u32)f2bf(v.y) << 16);
    u32 hi = (u32)f2bf(v.z) | ((u32)f2bf(v.w) << 16);
    ((uint2*)d)[i] = make_uint2(lo, hi);
  }
}

// ---------------- RoPE (1 wave = 1 row of 128) ----------------
__global__ __launch_bounds__(256) void rope_kernel(
    const u16* __restrict__ Qin, const u16* __restrict__ Kin,
    u16* __restrict__ Qout, u16* __restrict__ Kout,
    const float* __restrict__ cosT, const float* __restrict__ sinT) {
  int ten = blockIdx.y;
  const u16* in = ten ? Kin : Qin;
  u16* outp     = ten ? Kout : Qout;
  float scl     = ten ? 1.0f : 0.08838834764831845f;  // fold 1/sqrt(DH) into Q
  int row = blockIdx.x * 4 + (threadIdx.x >> 6);
  int j   = threadIdx.x & 63;
  int s   = row & (SQ - 1);
  const u16* r = in + (size_t)row * HD;
  u16* w = outp + (size_t)row * HD;
  float c  = cosT[s * HD + j];
  float si = sinT[s * HD + j];
  float a  = bf2f(r[j]);
  float b  = bf2f(r[j + 64]);
  float ev = bf2f(r[2 * j]);
  float od = bf2f(r[2 * j + 1]);
  w[j]      = f2bf((a * c - od * si) * scl);
  w[j + 64] = f2bf((b * c + ev * si) * scl);
}

// ---------------- V (b,h,s,dh) -> Vt (b,h,dh,s) ----------------
__global__ __launch_bounds__(256) void transpose_v(const u16* __restrict__ V,
                                                   u16* __restrict__ Vt) {
  __shared__ u16 tile[64][72];
  int sb = blockIdx.x, db = blockIdx.y, bh = blockIdx.z;
  int r  = threadIdx.x >> 3;
  int c8 = (threadIdx.x & 7) * 8;
  const u16* src = V + ((size_t)bh * SQ + sb * 64) * HD + db * 64;
#pragma unroll
  for (int p2 = 0; p2 < 2; p2++) {
    int row = p2 * 32 + r;
    u16x8 v = *(const u16x8*)(src + (size_t)row * HD + c8);
#pragma unroll
    for (int k2 = 0; k2 < 8; k2++) tile[row][c8 + k2] = v[k2];
  }
  __syncthreads();
  u16* dst = Vt + ((size_t)bh * HD + db * 64) * SQ + sb * 64;
#pragma unroll
  for (int p2 = 0; p2 < 2; p2++) {
    int dr = p2 * 32 + r;
    u16x8 o;
#pragma unroll
    for (int k2 = 0; k2 < 8; k2++) o[k2] = tile[c8 + k2][dr];
    *(u16x8*)(dst + (size_t)dr * SQ + c8) = o;
  }
}

// ---------------- GEMM C = A(M,K) * W(N,K)^T  (m97 structure) ----------------
template <int MODE>
__global__ __launch_bounds__(256) void gemm_bt(
    const u16* __restrict__ A,
    const u16* __restrict__ W0, const u16* __restrict__ W1, const u16* __restrict__ W2,
    u16* __restrict__ O0, u16* __restrict__ O1, u16* __restrict__ O2,
    float* __restrict__ Ofp) {
  __shared__ alignas(16) u16 lA[2][128 * 32];
  __shared__ alignas(16) u16 lB[2][128 * 32];
  int t = threadIdx.x;
  int l = t & 63, l15 = l & 15, lg = l >> 4;
  int wid = t >> 6, wr = wid >> 1, wc = wid & 1;
  int mi = blockIdx.x >> 4, ni = blockIdx.x & 15;
  int m0 = mi * 128, n0 = ni * 128;
  const u16* W = W0;
  u16* Ob = O0;
  if (MODE == 0) {
    if (blockIdx.y == 1) { W = W1; Ob = O1; }
    else if (blockIdx.y == 2) { W = W2; Ob = O2; }
  }
  const u16* Ag = A + (size_t)m0 * DIMD;
  const u16* Wg = W + (size_t)n0 * DIMD;
  int r0 = t >> 2, ch = (t & 3) * 8;

  f32x4 acc[4][4];
#pragma unroll
  for (int a1 = 0; a1 < 4; a1++)
#pragma unroll
    for (int b1 = 0; b1 < 4; b1++) acc[a1][b1] = (f32x4){0.f, 0.f, 0.f, 0.f};

  auto stage = [&](int buf, int kb) {
    int k0 = kb * 32;
    gld16(Ag + (size_t)r0 * DIMD + k0 + ch,        &lA[buf][t * 8]);
    gld16(Ag + (size_t)(r0 + 64) * DIMD + k0 + ch, &lA[buf][(t + 256) * 8]);
    gld16(Wg + (size_t)r0 * DIMD + k0 + ch,        &lB[buf][t * 8]);
    gld16(Wg + (size_t)(r0 + 64) * DIMD + k0 + ch, &lB[buf][(t + 256) * 8]);
  };

  stage(0, 0);
  __syncthreads();
#pragma unroll 2
  for (int kb = 0; kb < DIMD / 32; kb++) {
    if (kb + 1 < DIMD / 32) stage((kb + 1) & 1, kb + 1);
    int buf = kb & 1;
    s16x8 af[4], bfr[4];
#pragma unroll
    for (int rb = 0; rb < 4; rb++)
      af[rb] = *(const s16x8*)&lA[buf][(wr * 64 + rb * 16 + l15) * 32 + lg * 8];
#pragma unroll
    for (int cb = 0; cb < 4; cb++)
      bfr[cb] = *(const s16x8*)&lB[buf][(wc * 64 + cb * 16 + l15) * 32 + lg * 8];
#pragma unroll
    for (int rb = 0; rb < 4; rb++)
#pragma unroll
      for (int cb = 0; cb < 4; cb++)
        acc[rb][cb] = __builtin_amdgcn_mfma_f32_16x16x32_bf16(af[rb], bfr[cb], acc[rb][cb], 0, 0, 0);
    __syncthreads();
  }
#pragma unroll
  for (int rb = 0; rb < 4; rb++) {
#pragma unroll
    for (int cb = 0; cb < 4; cb++) {
#pragma unroll
      for (int i = 0; i < 4; i++) {
        float v = acc[rb][cb][i];
        int mm = m0 + wr * 64 + rb * 16 + lg * 4 + i;
        int nn = n0 + wc * 64 + cb * 16 + l15;
        if (MODE == 0) {
          int b = mm >> 11, s2 = mm & (SQ - 1), h = nn >> 7, dh = nn & (HD - 1);
          Ob[((size_t)(b * NH + h) * SQ + s2) * HD + dh] = f2bf(v);
        } else {
          Ofp[(size_t)mm * DIMD + nn] = v;
        }
      }
    }
  }
}

// ---------------- flash attention (LDS-staged, double-buffered, swizzled) ----
// grid: 512 blocks (flattened, XCD-swizzled). 8 waves/block, wave owns 16 q-rows.
// K tile [64][128] and Vt tile [128][64] in LDS; XOR swizzle byte^=((row&7)<<4)
// applied on the GLOBAL source address (LDS dest linear, per global_load_lds
// semantics) and on the ds_read address.
__global__ __launch_bounds__(512, 4) void attn_kernel(
    const u16* __restrict__ Q, const u16* __restrict__ K,
    const u16* __restrict__ Vt, u16* __restrict__ Aout) {
  __shared__ alignas(16) u16 Ksh[2][KBLK * HD];   // 2 x 16 KB
  __shared__ alignas(16) u16 Vsh[2][HD * KBLK];   // 2 x 16 KB
  __shared__ alignas(16) u16 Pl[8][16 * KBLK];    // 16 KB (per-wave, swizzled)
  int t = threadIdx.x;
  int wid = t >> 6, l = t & 63, l15 = l & 15, lg = l >> 4;
  // bijective XCD swizzle: 512 blocks -> each XCD gets 4 consecutive bh (4MB K/V in its L2)
  int orig = blockIdx.x;
  int bid = (orig & 7) * 64 + (orig >> 3);
  int qb = bid & 15, bh = bid >> 4;
  int q0 = qb * QBLK + wid * 16;
  const u16* Qb = Q + ((size_t)bh * SQ + q0) * HD;
  const u16* Kb = K + (size_t)bh * SQ * HD;
  const u16* Vb = Vt + (size_t)bh * HD * SQ;

  s16x8 qf[4];
#pragma unroll
  for (int ks = 0; ks < 4; ks++)
    qf[ks] = *(const s16x8*)(Qb + (size_t)l15 * HD + ks * 32 + lg * 8);

  // staging source offsets (inverse-swizzled so linear LDS == swizzled layout)
  int o0 = t * 16, o1 = t * 16 + 8192;
  int kr0 = o0 >> 8, kc0 = (o0 & 255) ^ ((kr0 & 7) << 4);
  int kr1 = o1 >> 8, kc1 = (o1 & 255) ^ ((kr1 & 7) << 4);
  int vr0 = o0 >> 7, vc0 = (o0 & 127) ^ ((vr0 & 7) << 4);
  int vr1 = o1 >> 7, vc1 = (o1 & 127) ^ ((vr1 & 7) << 4);

  auto stage = [&](int buf, int kb) {
    const u16* Kt = Kb + (size_t)kb * KBLK * HD;
    const u16* Vs = Vb + kb * KBLK;
    gld16(Kt + (size_t)kr0 * HD + (kc0 >> 1), &Ksh[buf][o0 >> 1]);
    gld16(Kt + (size_t)kr1 * HD + (kc1 >> 1), &Ksh[buf][o1 >> 1]);
    gld16(Vs + (size_t)vr0 * SQ + (vc0 >> 1), &Vsh[buf][o0 >> 1]);
    gld16(Vs + (size_t)vr1 * SQ + (vc1 >> 1), &Vsh[buf][o1 >> 1]);
  };

  f32x4 acc[8];
#pragma unroll
  for (int i = 0; i < 8; i++) acc[i] = (f32x4){0.f, 0.f, 0.f, 0.f};
  float m[4], lsum[4];
#pragma unroll
  for (int i = 0; i < 4; i++) { m[i] = -3.0e38f; lsum[i] = 0.f; }

  stage(0, 0);
  __syncthreads();

#pragma unroll 1
  for (int kb = 0; kb < SQ / KBLK; kb++) {
    int cur = kb & 1;
    if (kb + 1 < SQ / KBLK) stage(cur ^ 1, kb + 1);
    // ---- QK^T: 16 q-rows x 64 k-cols ----
    f32x4 sa[4];
#pragma unroll
    for (int cb = 0; cb < 4; cb++) sa[cb] = (f32x4){0.f, 0.f, 0.f, 0.f};
#pragma unroll
    for (int ks = 0; ks < 4; ks++) {
#pragma unroll
      for (int cb = 0; cb < 4; cb++) {
        int r = cb * 16 + l15;
        int off = r * 256 + ((ks * 64 + lg * 16) ^ ((r & 7) << 4));
        s16x8 kf = *(const s16x8*)((const char*)&Ksh[cur][0] + off);
        sa[cb] = __builtin_amdgcn_mfma_f32_16x16x32_bf16(qf[ks], kf, sa[cb], 0, 0, 0);
      }
    }
    // ---- online softmax; row = lg*4+i, 64 scores over 16 lanes x 4 blocks ----
    float rm[4];
#pragma unroll
    for (int i = 0; i < 4; i++)
      rm[i] = fmaxf(fmaxf(sa[0][i], sa[1][i]), fmaxf(sa[2][i], sa[3][i]));
#pragma unroll
    for (int d = 1; d < 16; d <<= 1)
#pragma unroll
      for (int i = 0; i < 4; i++) rm[i] = fmaxf(rm[i], __shfl_xor(rm[i], d));
    float al[4];
#pragma unroll
    for (int i = 0; i < 4; i++) {
      float mn = fmaxf(m[i], rm[i]);
      al[i] = __expf(m[i] - mn);
      m[i] = mn;
    }
#pragma unroll
    for (int cb = 0; cb < 4; cb++)
#pragma unroll
      for (int i = 0; i < 4; i++) sa[cb][i] = __expf(sa[cb][i] - m[i]);
    float ps[4];
#pragma unroll
    for (int i = 0; i < 4; i++) ps[i] = sa[0][i] + sa[1][i] + sa[2][i] + sa[3][i];
#pragma unroll
    for (int d = 1; d < 16; d <<= 1)
#pragma unroll
      for (int i = 0; i < 4; i++) ps[i] += __shfl_xor(ps[i], d);
#pragma unroll
    for (int i = 0; i < 4; i++) lsum[i] = lsum[i] * al[i] + ps[i];
#pragma unroll
    for (int c2 = 0; c2 < 8; c2++)
#pragma unroll
      for (int i = 0; i < 4; i++) acc[c2][i] *= al[i];
    // ---- P -> per-wave LDS (swizzled transpose to A-fragment layout) ----
#pragma unroll
    for (int cb = 0; cb < 4; cb++)
#pragma unroll
      for (int i = 0; i < 4; i++) {
        int row = lg * 4 + i;
        int off = row * 128 + ((2 * (cb * 16 + l15)) ^ ((row & 7) << 4));
        *(u16*)((char*)&Pl[wid][0] + off) = f2bf(sa[cb][i]);
      }
    asm volatile("s_waitcnt lgkmcnt(0)" ::: "memory");
    s16x8 pf[2];
#pragma unroll
    for (int k2 = 0; k2 < 2; k2++) {
      int off = l15 * 128 + ((k2 * 64 + lg * 16) ^ ((l15 & 7) << 4));
      pf[k2] = *(const s16x8*)((const char*)&Pl[wid][0] + off);
    }
    // ---- PV: out 16 q-rows x 128 dh ----
#pragma unroll
    for (int c2 = 0; c2 < 8; c2++) {
#pragma unroll
      for (int k2 = 0; k2 < 2; k2++) {
        int r = c2 * 16 + l15;
        int off = r * 128 + ((k2 * 64 + lg * 16) ^ ((r & 7) << 4));
        s16x8 vf = *(const s16x8*)((const char*)&Vsh[cur][0] + off);
        acc[c2] = __builtin_amdgcn_mfma_f32_16x16x32_bf16(pf[k2], vf, acc[c2], 0, 0, 0);
      }
    }
    __syncthreads();
  }
  float rin[4];
#pragma unroll
  for (int i = 0; i < 4; i++) rin[i] = 1.0f / lsum[i];
  int b = bh >> 4, h = bh & (NH - 1);
#pragma unroll
  for (int c2 = 0; c2 < 8; c2++) {
#pragma unroll
    for (int i = 0; i < 4; i++) {
      int q = q0 + lg * 4 + i;
      int dh = c2 * 16 + l15;
      Aout[((size_t)b * SQ + q) * DIMD + h * HD + dh] = f2bf(acc[c2][i] * rin[i]);
    }
  }
}

extern "C" void kernel_launch(void* const* d_in, const int* in_sizes, int n_in,
                              void* d_out, int out_size, void* d_ws, size_t ws_size,
                              hipStream_t stream) {
  (void)in_sizes; (void)n_in; (void)out_size; (void)ws_size;
  const float* x    = (const float*)d_in[0];
  const float* wq   = (const float*)d_in[1];
  const float* wk   = (const float*)d_in[2];
  const float* wv   = (const float*)d_in[3];
  const float* wo   = (const float*)d_in[4];
  const float* cosT = (const float*)d_in[5];
  const float* sinT = (const float*)d_in[6];
  float* out = (float*)d_out;

  char* p = (char*)d_ws;
  const size_t SZ_MD = (size_t)MR * DIMD * 2;    // 16.78 MB
  const size_t SZ_W  = (size_t)DIMD * DIMD * 2;  // 8.39 MB
  u16* xb   = (u16*)p; p += SZ_MD;
  u16* wqb  = (u16*)p; p += SZ_W;
  u16* wkb  = (u16*)p; p += SZ_W;
  u16* wvb  = (u16*)p; p += SZ_W;
  u16* wob  = (u16*)p; p += SZ_W;
  u16* Qraw = (u16*)p; p += SZ_MD;
  u16* Kraw = (u16*)p; p += SZ_MD;
  u16* Qr   = (u16*)p; p += SZ_MD;
  u16* Kr   = (u16*)p; p += SZ_MD;
  u16* Vb   = (u16*)p; p += SZ_MD;
  u16* Vt   = (u16*)p; p += SZ_MD;
  u16* attnout = Qraw;  // Qraw dead after rope; reuse

  cvt_bf16<<<1024, 256, 0, stream>>>(x,  xb,  MR * DIMD / 4);
  cvt_bf16<<<512,  256, 0, stream>>>(wq, wqb, DIMD * DIMD / 4);
  cvt_bf16<<<512,  256, 0, stream>>>(wk, wkb, DIMD * DIMD / 4);
  cvt_bf16<<<512,  256, 0, stream>>>(wv, wvb, DIMD * DIMD / 4);
  cvt_bf16<<<512,  256, 0, stream>>>(wo, wob, DIMD * DIMD / 4);

  gemm_bt<0><<<dim3(512, 3), 256, 0, stream>>>(xb, wqb, wkb, wvb, Qraw, Kraw, Vb, nullptr);
  rope_kernel<<<dim3(16384, 2), 256, 0, stream>>>(Qraw, Kraw, Qr, Kr, cosT, sinT);
  transpose_v<<<dim3(32, 2, 32), 256, 0, stream>>>(Vb, Vt);
  attn_kernel<<<512, 512, 0, stream>>>(Qr, Kr, Vt, attnout);
  gemm_bt<1><<<dim3(512, 1), 256, 0, stream>>>(attnout, wob, nullptr, nullptr,
                                               nullptr, nullptr, nullptr, out);
}

// Round 3
// 334.168 us; speedup vs baseline: 2.1857x; 1.1156x over previous
//
#include <hip/hip_runtime.h>

#define SQ   2048
#define DIMD 2048
#define NH   16
#define HD   128
#define MR   4096   // B*S
#define QBLK 128
#define KBLK 64

using u16 = unsigned short;
using u32 = unsigned int;
using s16x8 = __attribute__((ext_vector_type(8))) short;
using u16x8 = __attribute__((ext_vector_type(8))) unsigned short;
using f32x4 = __attribute__((ext_vector_type(4))) float;
using as3u  = __attribute__((address_space(3))) u32;
using as1u  = __attribute__((address_space(1))) u32;

__device__ __forceinline__ u16 f2bf(float f) {
  u32 x = __float_as_uint(f);
  return (u16)((x + 0x7fffu + ((x >> 16) & 1u)) >> 16);
}
__device__ __forceinline__ float bf2f(u16 u) {
  return __uint_as_float(((u32)u) << 16);
}
__device__ __forceinline__ void gld16(const void* g, void* l) {
  __builtin_amdgcn_global_load_lds((as1u*)g, (as3u*)l, 16, 0, 0);
}

// ---------------- fp32 -> bf16 convert ----------------
__global__ __launch_bounds__(256) void cvt_bf16(const float* __restrict__ s,
                                                u16* __restrict__ d, int n4) {
  int i = blockIdx.x * 256 + threadIdx.x;
  int st = gridDim.x * 256;
  for (; i < n4; i += st) {
    float4 v = ((const float4*)s)[i];
    u32 lo = (u32)f2bf(v.x) | ((u32)f2bf(v.y) << 16);
    u32 hi = (u32)f2bf(v.z) | ((u32)f2bf(v.w) << 16);
    ((uint2*)d)[i] = make_uint2(lo, hi);
  }
}

// ---------------- RoPE (1 wave = 1 row of 128) ----------------
__global__ __launch_bounds__(256) void rope_kernel(
    const u16* __restrict__ Qin, const u16* __restrict__ Kin,
    u16* __restrict__ Qout, u16* __restrict__ Kout,
    const float* __restrict__ cosT, const float* __restrict__ sinT) {
  int ten = blockIdx.y;
  const u16* in = ten ? Kin : Qin;
  u16* outp     = ten ? Kout : Qout;
  float scl     = ten ? 1.0f : 0.08838834764831845f;  // fold 1/sqrt(DH) into Q
  int row = blockIdx.x * 4 + (threadIdx.x >> 6);
  int j   = threadIdx.x & 63;
  int s   = row & (SQ - 1);
  const u16* r = in + (size_t)row * HD;
  u16* w = outp + (size_t)row * HD;
  float c  = cosT[s * HD + j];
  float si = sinT[s * HD + j];
  float a  = bf2f(r[j]);
  float b  = bf2f(r[j + 64]);
  float ev = bf2f(r[2 * j]);
  float od = bf2f(r[2 * j + 1]);
  w[j]      = f2bf((a * c - od * si) * scl);
  w[j + 64] = f2bf((b * c + ev * si) * scl);
}

// ---------------- V (b,h,s,dh) -> Vt (b,h,dh,s) ----------------
__global__ __launch_bounds__(256) void transpose_v(const u16* __restrict__ V,
                                                   u16* __restrict__ Vt) {
  __shared__ u16 tile[64][72];
  int sb = blockIdx.x, db = blockIdx.y, bh = blockIdx.z;
  int r  = threadIdx.x >> 3;
  int c8 = (threadIdx.x & 7) * 8;
  const u16* src = V + ((size_t)bh * SQ + sb * 64) * HD + db * 64;
#pragma unroll
  for (int p2 = 0; p2 < 2; p2++) {
    int row = p2 * 32 + r;
    u16x8 v = *(const u16x8*)(src + (size_t)row * HD + c8);
#pragma unroll
    for (int k2 = 0; k2 < 8; k2++) tile[row][c8 + k2] = v[k2];
  }
  __syncthreads();
  u16* dst = Vt + ((size_t)bh * HD + db * 64) * SQ + sb * 64;
#pragma unroll
  for (int p2 = 0; p2 < 2; p2++) {
    int dr = p2 * 32 + r;
    u16x8 o;
#pragma unroll
    for (int k2 = 0; k2 < 8; k2++) o[k2] = tile[c8 + k2][dr];
    *(u16x8*)(dst + (size_t)dr * SQ + c8) = o;
  }
}

// ---------------- GEMM C = A(M,K) * W(N,K)^T  (m97 structure) ----------------
template <int MODE>
__global__ __launch_bounds__(256) void gemm_bt(
    const u16* __restrict__ A,
    const u16* __restrict__ W0, const u16* __restrict__ W1, const u16* __restrict__ W2,
    u16* __restrict__ O0, u16* __restrict__ O1, u16* __restrict__ O2,
    float* __restrict__ Ofp) {
  __shared__ alignas(16) u16 lA[2][128 * 32];
  __shared__ alignas(16) u16 lB[2][128 * 32];
  int t = threadIdx.x;
  int l = t & 63, l15 = l & 15, lg = l >> 4;
  int wid = t >> 6, wr = wid >> 1, wc = wid & 1;
  int mi = blockIdx.x >> 4, ni = blockIdx.x & 15;
  int m0 = mi * 128, n0 = ni * 128;
  const u16* W = W0;
  u16* Ob = O0;
  if (MODE == 0) {
    if (blockIdx.y == 1) { W = W1; Ob = O1; }
    else if (blockIdx.y == 2) { W = W2; Ob = O2; }
  }
  const u16* Ag = A + (size_t)m0 * DIMD;
  const u16* Wg = W + (size_t)n0 * DIMD;
  int r0 = t >> 2, ch = (t & 3) * 8;

  f32x4 acc[4][4];
#pragma unroll
  for (int a1 = 0; a1 < 4; a1++)
#pragma unroll
    for (int b1 = 0; b1 < 4; b1++) acc[a1][b1] = (f32x4){0.f, 0.f, 0.f, 0.f};

  auto stage = [&](int buf, int kb) {
    int k0 = kb * 32;
    gld16(Ag + (size_t)r0 * DIMD + k0 + ch,        &lA[buf][t * 8]);
    gld16(Ag + (size_t)(r0 + 64) * DIMD + k0 + ch, &lA[buf][(t + 256) * 8]);
    gld16(Wg + (size_t)r0 * DIMD + k0 + ch,        &lB[buf][t * 8]);
    gld16(Wg + (size_t)(r0 + 64) * DIMD + k0 + ch, &lB[buf][(t + 256) * 8]);
  };

  stage(0, 0);
  __syncthreads();
#pragma unroll 2
  for (int kb = 0; kb < DIMD / 32; kb++) {
    if (kb + 1 < DIMD / 32) stage((kb + 1) & 1, kb + 1);
    int buf = kb & 1;
    s16x8 af[4], bfr[4];
#pragma unroll
    for (int rb = 0; rb < 4; rb++)
      af[rb] = *(const s16x8*)&lA[buf][(wr * 64 + rb * 16 + l15) * 32 + lg * 8];
#pragma unroll
    for (int cb = 0; cb < 4; cb++)
      bfr[cb] = *(const s16x8*)&lB[buf][(wc * 64 + cb * 16 + l15) * 32 + lg * 8];
#pragma unroll
    for (int rb = 0; rb < 4; rb++)
#pragma unroll
      for (int cb = 0; cb < 4; cb++)
        acc[rb][cb] = __builtin_amdgcn_mfma_f32_16x16x32_bf16(af[rb], bfr[cb], acc[rb][cb], 0, 0, 0);
    __syncthreads();
  }
#pragma unroll
  for (int rb = 0; rb < 4; rb++) {
#pragma unroll
    for (int cb = 0; cb < 4; cb++) {
#pragma unroll
      for (int i = 0; i < 4; i++) {
        float v = acc[rb][cb][i];
        int mm = m0 + wr * 64 + rb * 16 + lg * 4 + i;
        int nn = n0 + wc * 64 + cb * 16 + l15;
        if (MODE == 0) {
          int b = mm >> 11, s2 = mm & (SQ - 1), h = nn >> 7, dh = nn & (HD - 1);
          Ob[((size_t)(b * NH + h) * SQ + s2) * HD + dh] = f2bf(v);
        } else {
          Ofp[(size_t)mm * DIMD + nn] = v;
        }
      }
    }
  }
}

// ---------------- flash attention (swapped QK^T, in-lane softmax) ----------
// grid: 512 blocks (XCD-swizzled). 8 waves/block, wave owns 16 q-rows.
// S^T = mfma(K, Q): lane l15 = q, holds k = cb*16+lg*4+i -> row stats are
// 15 in-lane ops + 2 shfl_xor. Defer-max (THR=8) skips O-rescale on most
// tiles. P packed to 8B ds_write_b64 (XOR-swizzled both sides).
__global__ __launch_bounds__(512, 4) void attn_kernel(
    const u16* __restrict__ Q, const u16* __restrict__ K,
    const u16* __restrict__ Vt, u16* __restrict__ Aout) {
  __shared__ alignas(16) u16 Ksh[2][KBLK * HD];   // 2 x 16 KB
  __shared__ alignas(16) u16 Vsh[2][HD * KBLK];   // 2 x 16 KB
  __shared__ alignas(16) u16 Pl[8][16 * KBLK];    // 16 KB (per-wave, swizzled)
  int t = threadIdx.x;
  int wid = t >> 6, l = t & 63, l15 = l & 15, lg = l >> 4;
  int orig = blockIdx.x;
  int bid = (orig & 7) * 64 + (orig >> 3);
  int qb = bid & 15, bh = bid >> 4;
  int q0 = qb * QBLK + wid * 16;
  const u16* Qb = Q + ((size_t)bh * SQ + q0) * HD;
  const u16* Kb = K + (size_t)bh * SQ * HD;
  const u16* Vb = Vt + (size_t)bh * HD * SQ;

  s16x8 qf[4];
#pragma unroll
  for (int ks = 0; ks < 4; ks++)
    qf[ks] = *(const s16x8*)(Qb + (size_t)l15 * HD + ks * 32 + lg * 8);

  // staging source offsets (inverse-swizzled so linear LDS == swizzled layout)
  int o0 = t * 16, o1 = t * 16 + 8192;
  int kr0 = o0 >> 8, kc0 = (o0 & 255) ^ ((kr0 & 7) << 4);
  int kr1 = o1 >> 8, kc1 = (o1 & 255) ^ ((kr1 & 7) << 4);
  int vr0 = o0 >> 7, vc0 = (o0 & 127) ^ ((vr0 & 7) << 4);
  int vr1 = o1 >> 7, vc1 = (o1 & 127) ^ ((vr1 & 7) << 4);

  auto stage = [&](int buf, int kb) {
    const u16* Kt = Kb + (size_t)kb * KBLK * HD;
    const u16* Vs = Vb + kb * KBLK;
    gld16(Kt + (size_t)kr0 * HD + (kc0 >> 1), &Ksh[buf][o0 >> 1]);
    gld16(Kt + (size_t)kr1 * HD + (kc1 >> 1), &Ksh[buf][o1 >> 1]);
    gld16(Vs + (size_t)vr0 * SQ + (vc0 >> 1), &Vsh[buf][o0 >> 1]);
    gld16(Vs + (size_t)vr1 * SQ + (vc1 >> 1), &Vsh[buf][o1 >> 1]);
  };

  f32x4 acc[8];
#pragma unroll
  for (int i = 0; i < 8; i++) acc[i] = (f32x4){0.f, 0.f, 0.f, 0.f};
  float m = -3.0e38f, lsum = 0.f;

  stage(0, 0);
  __syncthreads();

#pragma unroll 1
  for (int kb = 0; kb < SQ / KBLK; kb++) {
    int cur = kb & 1;
    if (kb + 1 < SQ / KBLK) stage(cur ^ 1, kb + 1);
    // ---- S^T = K . Q^T : rows k (cb*16+lg*4+i), cols q (l15) ----
    f32x4 sa[4];
#pragma unroll
    for (int cb = 0; cb < 4; cb++) sa[cb] = (f32x4){0.f, 0.f, 0.f, 0.f};
    __builtin_amdgcn_s_setprio(1);
#pragma unroll
    for (int ks = 0; ks < 4; ks++) {
#pragma unroll
      for (int cb = 0; cb < 4; cb++) {
        int r = cb * 16 + l15;
        int off = r * 256 + ((ks * 64 + lg * 16) ^ ((r & 7) << 4));
        s16x8 kf = *(const s16x8*)((const char*)&Ksh[cur][0] + off);
        sa[cb] = __builtin_amdgcn_mfma_f32_16x16x32_bf16(kf, qf[ks], sa[cb], 0, 0, 0);
      }
    }
    __builtin_amdgcn_s_setprio(0);
    // ---- row stats: lane l15 owns q-row l15 ----
    float rm = sa[0][0];
#pragma unroll
    for (int cb = 0; cb < 4; cb++)
#pragma unroll
      for (int i = 0; i < 4; i++) rm = fmaxf(rm, sa[cb][i]);
    rm = fmaxf(rm, __shfl_xor(rm, 16));
    rm = fmaxf(rm, __shfl_xor(rm, 32));
    if (!__all(rm <= m + 8.0f)) {   // defer-max: rescale only on real growth
      float mn = fmaxf(m, rm);
      float al = __expf(m - mn);
      m = mn;
      float alq[4];
#pragma unroll
      for (int i = 0; i < 4; i++) alq[i] = __shfl(al, lg * 4 + i, 16);
#pragma unroll
      for (int c2 = 0; c2 < 8; c2++)
#pragma unroll
        for (int i = 0; i < 4; i++) acc[c2][i] *= alq[i];
      lsum *= al;
    }
    float ps = 0.f;
#pragma unroll
    for (int cb = 0; cb < 4; cb++)
#pragma unroll
      for (int i = 0; i < 4; i++) {
        sa[cb][i] = __expf(sa[cb][i] - m);
        ps += sa[cb][i];
      }
    ps += __shfl_xor(ps, 16);
    ps += __shfl_xor(ps, 32);
    lsum += ps;
    // ---- P -> per-wave LDS: row q=l15, cols k; packed 8B, swizzled ----
#pragma unroll
    for (int cb = 0; cb < 4; cb++) {
      u32 lo = (u32)f2bf(sa[cb][0]) | ((u32)f2bf(sa[cb][1]) << 16);
      u32 hi = (u32)f2bf(sa[cb][2]) | ((u32)f2bf(sa[cb][3]) << 16);
      int off = l15 * 128 + ((cb * 32 + lg * 8) ^ ((l15 & 7) << 4));
      *(uint2*)((char*)&Pl[wid][0] + off) = make_uint2(lo, hi);
    }
    asm volatile("s_waitcnt lgkmcnt(0)" ::: "memory");
    __builtin_amdgcn_sched_barrier(0);
    s16x8 pf[2];
#pragma unroll
    for (int k2 = 0; k2 < 2; k2++) {
      int off = l15 * 128 + ((k2 * 64 + lg * 16) ^ ((l15 & 7) << 4));
      pf[k2] = *(const s16x8*)((const char*)&Pl[wid][0] + off);
    }
    // ---- PV: out 16 q-rows x 128 dh ----
    __builtin_amdgcn_s_setprio(1);
#pragma unroll
    for (int c2 = 0; c2 < 8; c2++) {
#pragma unroll
      for (int k2 = 0; k2 < 2; k2++) {
        int r = c2 * 16 + l15;
        int off = r * 128 + ((k2 * 64 + lg * 16) ^ ((r & 7) << 4));
        s16x8 vf = *(const s16x8*)((const char*)&Vsh[cur][0] + off);
        acc[c2] = __builtin_amdgcn_mfma_f32_16x16x32_bf16(pf[k2], vf, acc[c2], 0, 0, 0);
      }
    }
    __builtin_amdgcn_s_setprio(0);
    __syncthreads();
  }
  float rin = 1.0f / lsum;
  float rq[4];
#pragma unroll
  for (int i = 0; i < 4; i++) rq[i] = __shfl(rin, lg * 4 + i, 16);
  int b = bh >> 4, h = bh & (NH - 1);
#pragma unroll
  for (int c2 = 0; c2 < 8; c2++) {
#pragma unroll
    for (int i = 0; i < 4; i++) {
      int q = q0 + lg * 4 + i;
      int dh = c2 * 16 + l15;
      Aout[((size_t)b * SQ + q) * DIMD + h * HD + dh] = f2bf(acc[c2][i] * rq[i]);
    }
  }
}

extern "C" void kernel_launch(void* const* d_in, const int* in_sizes, int n_in,
                              void* d_out, int out_size, void* d_ws, size_t ws_size,
                              hipStream_t stream) {
  (void)in_sizes; (void)n_in; (void)out_size; (void)ws_size;
  const float* x    = (const float*)d_in[0];
  const float* wq   = (const float*)d_in[1];
  const float* wk   = (const float*)d_in[2];
  const float* wv   = (const float*)d_in[3];
  const float* wo   = (const float*)d_in[4];
  const float* cosT = (const float*)d_in[5];
  const float* sinT = (const float*)d_in[6];
  float* out = (float*)d_out;

  char* p = (char*)d_ws;
  const size_t SZ_MD = (size_t)MR * DIMD * 2;    // 16.78 MB
  const size_t SZ_W  = (size_t)DIMD * DIMD * 2;  // 8.39 MB
  u16* xb   = (u16*)p; p += SZ_MD;
  u16* wqb  = (u16*)p; p += SZ_W;
  u16* wkb  = (u16*)p; p += SZ_W;
  u16* wvb  = (u16*)p; p += SZ_W;
  u16* wob  = (u16*)p; p += SZ_W;
  u16* Qraw = (u16*)p; p += SZ_MD;
  u16* Kraw = (u16*)p; p += SZ_MD;
  u16* Qr   = (u16*)p; p += SZ_MD;
  u16* Kr   = (u16*)p; p += SZ_MD;
  u16* Vb   = (u16*)p; p += SZ_MD;
  u16* Vt   = (u16*)p; p += SZ_MD;
  u16* attnout = Qraw;  // Qraw dead after rope; reuse

  cvt_bf16<<<1024, 256, 0, stream>>>(x,  xb,  MR * DIMD / 4);
  cvt_bf16<<<512,  256, 0, stream>>>(wq, wqb, DIMD * DIMD / 4);
  cvt_bf16<<<512,  256, 0, stream>>>(wk, wkb, DIMD * DIMD / 4);
  cvt_bf16<<<512,  256, 0, stream>>>(wv, wvb, DIMD * DIMD / 4);
  cvt_bf16<<<512,  256, 0, stream>>>(wo, wob, DIMD * DIMD / 4);

  gemm_bt<0><<<dim3(512, 3), 256, 0, stream>>>(xb, wqb, wkb, wvb, Qraw, Kraw, Vb, nullptr);
  rope_kernel<<<dim3(16384, 2), 256, 0, stream>>>(Qraw, Kraw, Qr, Kr, cosT, sinT);
  transpose_v<<<dim3(32, 2, 32), 256, 0, stream>>>(Vb, Vt);
  attn_kernel<<<512, 512, 0, stream>>>(Qr, Kr, Vt, attnout);
  gemm_bt<1><<<dim3(512, 1), 256, 0, stream>>>(attnout, wob, nullptr, nullptr,
                                               nullptr, nullptr, nullptr, out);
}